// Round 1
// baseline (440.191 us; speedup 1.0000x reference)
//
#include <hip/hip_runtime.h>
#include <hip/hip_bf16.h>
#include <math.h>

#define B_ 4
#define N_ 4096
#define F_ 128
#define K_ 32
#define EPS_ 1e-8f

typedef __attribute__((ext_vector_type(8))) __bf16 bf16x8;
typedef __attribute__((ext_vector_type(4))) float f32x4;

// ws float-index layout
#define WS_SSOFT   0          // 131072
#define WS_SQ      131072     // 4096
#define WS_SS      135168     // 1024 (memset to 0)
#define WS_WF      136192     // bf16 frags: B*N*64 bf16 = 2MB = 524288 float-equiv
#define WS_OADJP   660480     // 1024 blocks * 1024 = 1048576
#define WS_NUMDEN  1709056    // 2048
#define WS_PEMB    1711104    // 128 blocks * 4096 = 524288
#define WS_OADJ    2235392    // 4096 (reduced)
#define WS_H       2239488    // B*N ints

// ---- K1: s_soft [N,K] fp32, sq[n]=sum_k s^2, ss[K,K] += s_soft^T s_soft ----
__global__ void k_ssoft(const float* __restrict__ logits, float* __restrict__ s_soft,
                        float* __restrict__ sq, float* __restrict__ ss, float t2) {
  __shared__ float sl[64][33];
  int t = threadIdx.x;
  int rowbase = blockIdx.x * 64;
  if (t < 64) {
    int n = rowbase + t;
    float z[32];
    float mx = -1e30f;
    for (int k = 0; k < 32; ++k) { z[k] = logits[n*32+k] / t2; mx = fmaxf(mx, z[k]); }
    float s = 0.f;
    for (int k = 0; k < 32; ++k) { z[k] = expf(z[k]-mx); s += z[k]; }
    float sqa = 0.f;
    for (int k = 0; k < 32; ++k) {
      float v = z[k] / s;
      s_soft[n*32+k] = v;
      sl[t][k] = v;
      sqa += v*v;
    }
    sq[n] = sqa;
  }
  __syncthreads();
  for (int pp = 0; pp < 4; ++pp) {
    int p = pp*256 + t;
    int k = p >> 5, l = p & 31;
    float a = 0.f;
    for (int r = 0; r < 64; ++r) a += sl[r][k]*sl[r][l];
    atomicAdd(&ss[p], a);
  }
}

// ---- K2: gumbel-softmax hard sample -> s_sample (d_out) + argmax h ----
__global__ void k_gumbel(const float* __restrict__ logits, const float* __restrict__ gum,
                         float* __restrict__ s_sample, int* __restrict__ h, float t1) {
  int i = blockIdx.x*256 + threadIdx.x;   // [0, B*N)
  int n = i & (N_-1);
  float z[32];
  float mx = -1e30f;
  for (int k = 0; k < 32; ++k) { z[k] = logits[n*32+k]/t1 + gum[(size_t)i*32+k]; mx = fmaxf(mx, z[k]); }
  float s = 0.f;
  for (int k = 0; k < 32; ++k) { z[k] = expf(z[k]-mx); s += z[k]; }
  int am = 0; float best = -1.f;
  for (int k = 0; k < 32; ++k) { z[k] = z[k]/s; if (z[k] > best) { best = z[k]; am = k; } }
  for (int k = 0; k < 32; ++k) {
    float yh = (k==am) ? 1.f : 0.f;
    s_sample[(size_t)i*32+k] = (yh - z[k]) + z[k] + EPS_;
  }
  h[i] = am;
}

// ---- K3: build W in MFMA B-fragment order: [b][t32][c][lane] bf16x8 ----
__global__ void k_wfrag(const float* __restrict__ s_soft, const int* __restrict__ h,
                        bf16x8* __restrict__ wf) {
  int i = blockIdx.x*256 + threadIdx.x;   // [0, 4*128*4*64)
  int lane = i & 63;
  int c = (i >> 6) & 3;
  int tt = (i >> 8) & 127;
  int b = i >> 15;
  int col = c*16 + (lane & 15);
  int m0 = tt*32 + (lane >> 4)*8;
  bf16x8 v;
  if (col < 32) {
    for (int j = 0; j < 8; ++j) v[j] = (__bf16)s_soft[(m0+j)*32 + col];
  } else {
    int cc = col - 32;
    for (int j = 0; j < 8; ++j) v[j] = (__bf16)((h[b*N_ + m0 + j] == cc) ? 1.f : 0.f);
  }
  wf[i] = v;
}

#define NT(p) __builtin_nontemporal_load((const f32x4*)(p))

// ---- K4: Y = adj @ [s_soft | H]; direct per-lane A-fragment loads from global.
// No LDS staging for A: each adj element feeds exactly one lane's MFMA fragment,
// so the global->LDS round trip (and its 2 barriers/chunk) was pure overhead.
// grid = B * 32 rowblocks * 8 splitm = 1024; block = 128 rows x 64 cols, m-chunk 512.
__launch_bounds__(256, 4)
__global__ void k_gemm(const float* __restrict__ adj, const bf16x8* __restrict__ wf,
                       const float* __restrict__ s_soft, const float* __restrict__ sq,
                       const int* __restrict__ h, float* __restrict__ numden_p,
                       float* __restrict__ oadjp) {
  __shared__ float oal[1024];
  __shared__ float rn[4], rd[4];
  int t = threadIdx.x;
  int w = t >> 6, l = t & 63;
  int lr = l & 15, lhi = l >> 4;
  int bid = blockIdx.x;
  int sp = bid & 7, r = (bid >> 3) & 31, b = bid >> 8;

  for (int i = t; i < 1024; i += 256) oal[i] = 0.f;
  __syncthreads();

  int row0 = r*128;
  int m0 = sp*512;
  int rowA = row0 + w*32 + lr;          // rt=0 row for this lane

  // lane's A-fragment: rows {rowA, rowA+16}, k-slice lhi*8..lhi*8+8 of each 32-chunk
  const float* pA0 = adj + (size_t)b*N_*N_ + (size_t)rowA*N_ + m0 + lhi*8;
  const float* pA1 = pA0 + (size_t)16*N_;
  const bf16x8* pw = wf + ((size_t)b*128 + (m0 >> 5))*256 + l;

  f32x4 acc00 = {0,0,0,0}, acc01 = {0,0,0,0}, acc02 = {0,0,0,0}, acc03 = {0,0,0,0};
  f32x4 acc10 = {0,0,0,0}, acc11 = {0,0,0,0}, acc12 = {0,0,0,0}, acc13 = {0,0,0,0};

  // prime chunk 0
  f32x4 a0lo = NT(pA0), a0hi = NT(pA0 + 4);
  f32x4 a1lo = NT(pA1), a1hi = NT(pA1 + 4);
  bf16x8 wc0 = pw[0], wc1 = pw[64], wc2 = pw[128], wc3 = pw[192];

  #pragma unroll 1
  for (int c = 0; c < 16; ++c) {
    f32x4 n0lo, n0hi, n1lo, n1hi;
    bf16x8 wn0, wn1, wn2, wn3;
    if (c < 15) {
      pA0 += 32; pA1 += 32; pw += 256;
      n0lo = NT(pA0); n0hi = NT(pA0 + 4);
      n1lo = NT(pA1); n1hi = NT(pA1 + 4);
      wn0 = pw[0]; wn1 = pw[64]; wn2 = pw[128]; wn3 = pw[192];
    }
    bf16x8 fa0, fa1;
    #pragma unroll
    for (int j = 0; j < 4; ++j) {
      fa0[j]   = (__bf16)a0lo[j];
      fa0[j+4] = (__bf16)a0hi[j];
      fa1[j]   = (__bf16)a1lo[j];
      fa1[j+4] = (__bf16)a1hi[j];
    }
    acc00 = __builtin_amdgcn_mfma_f32_16x16x32_bf16(fa0, wc0, acc00, 0, 0, 0);
    acc01 = __builtin_amdgcn_mfma_f32_16x16x32_bf16(fa0, wc1, acc01, 0, 0, 0);
    acc02 = __builtin_amdgcn_mfma_f32_16x16x32_bf16(fa0, wc2, acc02, 0, 0, 0);
    acc03 = __builtin_amdgcn_mfma_f32_16x16x32_bf16(fa0, wc3, acc03, 0, 0, 0);
    acc10 = __builtin_amdgcn_mfma_f32_16x16x32_bf16(fa1, wc0, acc10, 0, 0, 0);
    acc11 = __builtin_amdgcn_mfma_f32_16x16x32_bf16(fa1, wc1, acc11, 0, 0, 0);
    acc12 = __builtin_amdgcn_mfma_f32_16x16x32_bf16(fa1, wc2, acc12, 0, 0, 0);
    acc13 = __builtin_amdgcn_mfma_f32_16x16x32_bf16(fa1, wc3, acc13, 0, 0, 0);
    if (c < 15) {
      a0lo = n0lo; a0hi = n0hi; a1lo = n1lo; a1hi = n1hi;
      wc0 = wn0; wc1 = wn1; wc2 = wn2; wc3 = wn3;
    }
  }

  // epilogue: C-frag lane l holds col = c*16 + (l&15), rows row0 + w*32 + rt*16 + (l>>4)*4 + i
  float numacc = 0.f, denacc = 0.f;
  {
    f32x4 a0s[2] = {acc00, acc10}, a1s[2] = {acc01, acc11};
    f32x4 a2s[2] = {acc02, acc12}, a3s[2] = {acc03, acc13};
    int wrow0 = row0 + w*32;
    #pragma unroll
    for (int rt = 0; rt < 2; ++rt) {
      int rbase = wrow0 + rt*16 + lhi*4;
      #pragma unroll
      for (int i = 0; i < 4; ++i) {
        int row = rbase + i;
        float sqv = sq[row];
        int hv = h[b*N_ + row];
        numacc += a0s[rt][i] * s_soft[row*32 + lr];
        numacc += a1s[rt][i] * s_soft[row*32 + 16 + lr];
        float v2 = a2s[rt][i], v3 = a3s[rt][i];
        denacc += (v2 + v3) * sqv;
        atomicAdd(&oal[hv*32 + lr], v2);
        atomicAdd(&oal[hv*32 + 16 + lr], v3);
      }
    }
  }
  for (int off = 32; off; off >>= 1) {
    numacc += __shfl_down(numacc, off);
    denacc += __shfl_down(denacc, off);
  }
  if (l == 0) { rn[w] = numacc; rd[w] = denacc; }
  __syncthreads();
  if (t == 0) {
    numden_p[bid] = rn[0]+rn[1]+rn[2]+rn[3];
    numden_p[1024 + bid] = rd[0]+rd[1]+rd[2]+rd[3];
  }
  for (int i = t; i < 1024; i += 256) oadjp[(size_t)bid*1024 + i] = oal[i];
}

// ---- K5: out_emb partials: [128 blocks][32*128] ----
__global__ void k_outemb(const float* __restrict__ emb, const int* __restrict__ h,
                         float* __restrict__ pemb) {
  __shared__ float accl[32*128];
  int t = threadIdx.x;
  for (int i = t; i < 4096; i += 256) accl[i] = 0.f;
  __syncthreads();
  int b = blockIdx.x >> 5;
  int n0 = (blockIdx.x & 31) * 128;
  int f = t & 127, rr = t >> 7;
  for (int it = 0; it < 64; ++it) {
    int n = n0 + it*2 + rr;
    float v = emb[((size_t)b*N_ + n)*F_ + f];
    int hv = h[b*N_ + n];
    atomicAdd(&accl[hv*128 + f], v);
  }
  __syncthreads();
  for (int i = t; i < 4096; i += 256) pemb[(size_t)blockIdx.x*4096 + i] = accl[i];
}

// ---- K6: reduce partials (blocks 0..15: oadj; 16..79: out_emb -> d_out) ----
__global__ void k_reduce(const float* __restrict__ oadjp, const float* __restrict__ pemb,
                         float* __restrict__ oadj, float* __restrict__ out_emb) {
  int blk = blockIdx.x;
  if (blk < 16) {
    int i = blk*256 + threadIdx.x;      // [0,4096)
    int b = i >> 10, ii = i & 1023;
    float s = 0.f;
    const float* p = oadjp + (size_t)(b*256)*1024 + ii;
    for (int j = 0; j < 256; ++j) s += p[(size_t)j*1024];
    oadj[i] = s;
  } else {
    int i = (blk-16)*256 + threadIdx.x; // [0,16384)
    int b = i >> 12, ii = i & 4095;
    float s = 0.f;
    const float* p = pemb + (size_t)(b*32)*4096 + ii;
    for (int j = 0; j < 32; ++j) s += p[(size_t)j*4096];
    out_emb[i] = s;
  }
}

// ---- K7: finalize out_adj + scalars ----
__global__ void k_final(const float* __restrict__ numden_p, const float* __restrict__ oadj,
                        const float* __restrict__ ss, float* __restrict__ dout) {
  __shared__ float dsh[128];
  __shared__ float red[256];
  __shared__ float nd[8];
  int t = threadIdx.x;
  if (t < 8) {
    int b = t & 3;
    const float* p = numden_p + (t >> 2)*1024 + b*256;
    float s = 0.f;
    for (int j = 0; j < 256; ++j) s += p[j];
    nd[t] = s;
  }
  if (t >= 64 && t < 192) {
    int i = t - 64;
    int b = i >> 5, k = i & 31;
    float s = 0.f;
    for (int l = 0; l < 32; ++l) if (l != k) s += oadj[b*1024 + k*32 + l];
    dsh[i] = sqrtf(s) + EPS_;
  }
  __syncthreads();
  for (int i = t; i < 4096; i += 256) {
    int b = i >> 10, k = (i >> 5) & 31, l = i & 31;
    float v = (k == l) ? 0.f : oadj[i] / (dsh[b*32+k] * dsh[b*32+l]);
    dout[16384 + i] = v;
  }
  float a = 0.f;
  for (int i = t; i < 1024; i += 256) { float v = ss[i]; a += v*v; }
  red[t] = a; __syncthreads();
  for (int s2 = 128; s2; s2 >>= 1) { if (t < s2) red[t] += red[t+s2]; __syncthreads(); }
  float fro = sqrtf(red[0]);
  __syncthreads();
  float c = 0.f;
  float inv = 1.f / fro;
  float dk = (float)(1.0 / sqrt(32.0));
  for (int i = t; i < 1024; i += 256) {
    int k = i >> 5, l = i & 31;
    float v = ss[i]*inv - ((k == l) ? dk : 0.f);
    c += v*v;
  }
  red[t] = c; __syncthreads();
  for (int s2 = 128; s2; s2 >>= 1) { if (t < s2) red[t] += red[t+s2]; __syncthreads(); }
  if (t == 0) {
    dout[544769] = sqrtf(red[0]);
    float s = 0.f;
    for (int b = 0; b < 4; ++b) s += nd[b] / nd[4+b];
    dout[544768] = -s*0.25f;
  }
}

extern "C" void kernel_launch(void* const* d_in, const int* in_sizes, int n_in,
                              void* d_out, int out_size, void* d_ws, size_t ws_size,
                              hipStream_t stream) {
  const float* emb    = (const float*)d_in[0];
  const float* adj    = (const float*)d_in[1];
  const float* logits = (const float*)d_in[2];
  const float* gum    = (const float*)d_in[3];
  float* out = (float*)d_out;
  float* ws  = (float*)d_ws;

  float t1 = 0.99995f;
  float t2 = (float)(0.99995 * 0.99995);

  float* s_soft = ws + WS_SSOFT;
  float* sq     = ws + WS_SQ;
  float* ss     = ws + WS_SS;
  bf16x8* wf    = (bf16x8*)(ws + WS_WF);
  float* oadjp  = ws + WS_OADJP;
  float* ndp    = ws + WS_NUMDEN;
  float* pemb   = ws + WS_PEMB;
  float* oadj   = ws + WS_OADJ;
  int* hbuf     = (int*)(ws + WS_H);

  (void)hipMemsetAsync(ss, 0, 1024 * sizeof(float), stream);

  k_ssoft <<<64, 256, 0, stream>>>(logits, s_soft, sq, ss, t2);
  k_gumbel<<<64, 256, 0, stream>>>(logits, gum, out + 20480, hbuf, t1);
  k_wfrag <<<512, 256, 0, stream>>>(s_soft, hbuf, wf);
  k_gemm  <<<1024, 256, 0, stream>>>(adj, wf, s_soft, sq, hbuf, ndp, oadjp);
  k_outemb<<<128, 256, 0, stream>>>(emb, hbuf, pemb);
  k_reduce<<<80, 256, 0, stream>>>(oadjp, pemb, oadj, out);
  k_final <<<1, 256, 0, stream>>>(ndp, oadj, ss, out);
}

// Round 2
// 424.901 us; speedup vs baseline: 1.0360x; 1.0360x over previous
//
#include <hip/hip_runtime.h>
#include <hip/hip_bf16.h>
#include <math.h>

#define B_ 4
#define N_ 4096
#define F_ 128
#define K_ 32
#define EPS_ 1e-8f

typedef __attribute__((ext_vector_type(8))) __bf16 bf16x8;
typedef __attribute__((ext_vector_type(4))) float f32x4;

// ws float-index layout
#define WS_SSOFT   0          // 131072
#define WS_SQ      131072     // 4096
#define WS_SS      135168     // 1024 (memset to 0)
#define WS_WFS     136192     // [N/32][2][64] bf16x8 = 256KB = 65536 float-equiv
#define WS_WFH     201728     // [B][N/32][2][64] bf16x8 = 1MB = 262144 float-equiv
#define WS_OADJP   463872     // 1024 blocks * 1024 = 1048576
#define WS_NUMDEN  1512448    // 2048
#define WS_PEMB    1514496    // 256 blocks * 4096 = 1048576
#define WS_OADJ    2563072    // 4096 (reduced)
#define WS_H       2567168    // B*N ints

// ---- K_pre: fused s_soft softmax + ss partial + gumbel hard-sample + W-fragment build.
// Block r owns rows n0 = r*64 .. n0+64. Fragments for t32 in {2r, 2r+1} are fully
// determined by these rows, so everything stays in LDS — no global round-trip.
__global__ void k_pre(const float* __restrict__ logits, const float* __restrict__ gum,
                      float* __restrict__ s_soft, float* __restrict__ sq,
                      float* __restrict__ ss, float* __restrict__ s_sample,
                      int* __restrict__ h, bf16x8* __restrict__ wfs,
                      bf16x8* __restrict__ wfh, float t1, float t2) {
  __shared__ float sl[64][33];
  __shared__ int hl[4][64];
  int t = threadIdx.x;
  int r = blockIdx.x;
  int n0 = r * 64;

  // phase 1: soft softmax (64 rows, t<64)
  if (t < 64) {
    int n = n0 + t;
    float z[32];
    float mx = -1e30f;
    for (int k = 0; k < 32; ++k) { z[k] = logits[n*32+k] / t2; mx = fmaxf(mx, z[k]); }
    float s = 0.f;
    for (int k = 0; k < 32; ++k) { z[k] = expf(z[k]-mx); s += z[k]; }
    float sqa = 0.f;
    for (int k = 0; k < 32; ++k) {
      float v = z[k] / s;
      s_soft[n*32+k] = v;
      sl[t][k] = v;
      sqa += v*v;
    }
    sq[n] = sqa;
  }

  // phase 2: gumbel hard sample, thread t -> (b = t>>6, row n0 + (t&63))
  {
    int b = t >> 6, nn = t & 63;
    int n = n0 + nn;
    size_t i = (size_t)b * N_ + n;
    float z[32];
    float mx = -1e30f;
    for (int k = 0; k < 32; ++k) { z[k] = logits[n*32+k]/t1 + gum[i*32+k]; mx = fmaxf(mx, z[k]); }
    float s = 0.f;
    for (int k = 0; k < 32; ++k) { z[k] = expf(z[k]-mx); s += z[k]; }
    int am = 0; float best = -1.f;
    for (int k = 0; k < 32; ++k) { z[k] = z[k]/s; if (z[k] > best) { best = z[k]; am = k; } }
    for (int k = 0; k < 32; ++k) {
      float yh = (k==am) ? 1.f : 0.f;
      s_sample[i*32+k] = (yh - z[k]) + z[k] + EPS_;
    }
    h[i] = am;
    hl[b][nn] = am;
  }
  __syncthreads();

  // phase 3: ss[K,K] partial accumulation from sl
  for (int pp = 0; pp < 4; ++pp) {
    int p = pp*256 + t;
    int k = p >> 5, l = p & 31;
    float a = 0.f;
    for (int rr = 0; rr < 64; ++rr) a += sl[rr][k]*sl[rr][l];
    atomicAdd(&ss[p], a);
  }

  // phase 4: wfs fragments (batch-independent s_soft columns 0..31)
  // layout: wfs[(t32*2 + c)*64 + lane]; this block emits t32 in {2r,2r+1}
  {
    int lane = t & 63;
    int c = (t >> 6) & 1;
    int tts = t >> 7;               // 0..1
    int col = c*16 + (lane & 15);
    int lrow = tts*32 + (lane >> 4)*8;
    bf16x8 v;
    #pragma unroll
    for (int j = 0; j < 8; ++j) v[j] = (__bf16)sl[lrow+j][col];
    wfs[((size_t)(2*r + tts)*2 + c)*64 + lane] = v;
  }

  // phase 5: wfh fragments (one-hot columns 32..63), 4 batches
  for (int it = 0; it < 4; ++it) {
    int p = it*256 + t;
    int lane = p & 63;
    int c = (p >> 6) & 1;
    int tts = (p >> 7) & 1;
    int b = p >> 8;
    int cc = c*16 + (lane & 15);
    int lrow = tts*32 + (lane >> 4)*8;
    bf16x8 v;
    #pragma unroll
    for (int j = 0; j < 8; ++j) v[j] = (__bf16)((hl[b][lrow+j] == cc) ? 1.f : 0.f);
    wfh[(((size_t)b*(N_/32) + 2*r + tts)*2 + c)*64 + lane] = v;
  }
}

#define NT(p) __builtin_nontemporal_load((const f32x4*)(p))

// ---- K_gemm: Y = adj @ [s_soft | H]; direct per-lane A-fragment loads from global.
// grid = B * 32 rowblocks * 8 splitm = 1024; block = 128 rows x 64 cols, m-chunk 512.
__launch_bounds__(256, 4)
__global__ void k_gemm(const float* __restrict__ adj, const bf16x8* __restrict__ wfs,
                       const bf16x8* __restrict__ wfh,
                       const float* __restrict__ s_soft, const float* __restrict__ sq,
                       const int* __restrict__ h, float* __restrict__ numden_p,
                       float* __restrict__ oadjp) {
  __shared__ float oal[1024];
  __shared__ float rn[4], rd[4];
  int t = threadIdx.x;
  int w = t >> 6, l = t & 63;
  int lr = l & 15, lhi = l >> 4;
  int bid = blockIdx.x;
  int sp = bid & 7, r = (bid >> 3) & 31, b = bid >> 8;

  for (int i = t; i < 1024; i += 256) oal[i] = 0.f;
  __syncthreads();

  int row0 = r*128;
  int m0 = sp*512;
  int rowA = row0 + w*32 + lr;          // rt=0 row for this lane

  const float* pA0 = adj + (size_t)b*N_*N_ + (size_t)rowA*N_ + m0 + lhi*8;
  const float* pA1 = pA0 + (size_t)16*N_;
  const bf16x8* pws = wfs + (size_t)(m0 >> 5)*128 + l;
  const bf16x8* pwh = wfh + ((size_t)b*(N_/32) + (m0 >> 5))*128 + l;

  f32x4 acc00 = {0,0,0,0}, acc01 = {0,0,0,0}, acc02 = {0,0,0,0}, acc03 = {0,0,0,0};
  f32x4 acc10 = {0,0,0,0}, acc11 = {0,0,0,0}, acc12 = {0,0,0,0}, acc13 = {0,0,0,0};

  // prime chunk 0
  f32x4 a0lo = NT(pA0), a0hi = NT(pA0 + 4);
  f32x4 a1lo = NT(pA1), a1hi = NT(pA1 + 4);
  bf16x8 wc0 = pws[0], wc1 = pws[64], wc2 = pwh[0], wc3 = pwh[64];

  #pragma unroll 1
  for (int c = 0; c < 16; ++c) {
    f32x4 n0lo, n0hi, n1lo, n1hi;
    bf16x8 wn0, wn1, wn2, wn3;
    if (c < 15) {
      pA0 += 32; pA1 += 32; pws += 128; pwh += 128;
      n0lo = NT(pA0); n0hi = NT(pA0 + 4);
      n1lo = NT(pA1); n1hi = NT(pA1 + 4);
      wn0 = pws[0]; wn1 = pws[64]; wn2 = pwh[0]; wn3 = pwh[64];
    }
    bf16x8 fa0, fa1;
    #pragma unroll
    for (int j = 0; j < 4; ++j) {
      fa0[j]   = (__bf16)a0lo[j];
      fa0[j+4] = (__bf16)a0hi[j];
      fa1[j]   = (__bf16)a1lo[j];
      fa1[j+4] = (__bf16)a1hi[j];
    }
    acc00 = __builtin_amdgcn_mfma_f32_16x16x32_bf16(fa0, wc0, acc00, 0, 0, 0);
    acc01 = __builtin_amdgcn_mfma_f32_16x16x32_bf16(fa0, wc1, acc01, 0, 0, 0);
    acc02 = __builtin_amdgcn_mfma_f32_16x16x32_bf16(fa0, wc2, acc02, 0, 0, 0);
    acc03 = __builtin_amdgcn_mfma_f32_16x16x32_bf16(fa0, wc3, acc03, 0, 0, 0);
    acc10 = __builtin_amdgcn_mfma_f32_16x16x32_bf16(fa1, wc0, acc10, 0, 0, 0);
    acc11 = __builtin_amdgcn_mfma_f32_16x16x32_bf16(fa1, wc1, acc11, 0, 0, 0);
    acc12 = __builtin_amdgcn_mfma_f32_16x16x32_bf16(fa1, wc2, acc12, 0, 0, 0);
    acc13 = __builtin_amdgcn_mfma_f32_16x16x32_bf16(fa1, wc3, acc13, 0, 0, 0);
    if (c < 15) {
      a0lo = n0lo; a0hi = n0hi; a1lo = n1lo; a1hi = n1hi;
      wc0 = wn0; wc1 = wn1; wc2 = wn2; wc3 = wn3;
    }
  }

  // epilogue: C-frag lane l holds col = c*16 + (l&15), rows row0 + w*32 + rt*16 + (l>>4)*4 + i
  float numacc = 0.f, denacc = 0.f;
  {
    f32x4 a0s[2] = {acc00, acc10}, a1s[2] = {acc01, acc11};
    f32x4 a2s[2] = {acc02, acc12}, a3s[2] = {acc03, acc13};
    int wrow0 = row0 + w*32;
    #pragma unroll
    for (int rt = 0; rt < 2; ++rt) {
      int rbase = wrow0 + rt*16 + lhi*4;
      #pragma unroll
      for (int i = 0; i < 4; ++i) {
        int row = rbase + i;
        float sqv = sq[row];
        int hv = h[b*N_ + row];
        numacc += a0s[rt][i] * s_soft[row*32 + lr];
        numacc += a1s[rt][i] * s_soft[row*32 + 16 + lr];
        float v2 = a2s[rt][i], v3 = a3s[rt][i];
        denacc += (v2 + v3) * sqv;
        atomicAdd(&oal[hv*32 + lr], v2);
        atomicAdd(&oal[hv*32 + 16 + lr], v3);
      }
    }
  }
  for (int off = 32; off; off >>= 1) {
    numacc += __shfl_down(numacc, off);
    denacc += __shfl_down(denacc, off);
  }
  if (l == 0) { rn[w] = numacc; rd[w] = denacc; }
  __syncthreads();
  if (t == 0) {
    numden_p[bid] = rn[0]+rn[1]+rn[2]+rn[3];
    numden_p[1024 + bid] = rd[0]+rd[1]+rd[2]+rd[3];
  }
  for (int i = t; i < 1024; i += 256) oadjp[(size_t)bid*1024 + i] = oal[i];
}

// ---- K5: out_emb partials: 256 blocks (b = blk>>6, 64-row chunk), [256][32*128] ----
__global__ void k_outemb(const float* __restrict__ emb, const int* __restrict__ h,
                         float* __restrict__ pemb) {
  __shared__ float accl[32*128];
  int t = threadIdx.x;
  for (int i = t; i < 4096; i += 256) accl[i] = 0.f;
  __syncthreads();
  int b = blockIdx.x >> 6;
  int n0 = (blockIdx.x & 63) * 64;
  int f = t & 127, rr = t >> 7;
  for (int it = 0; it < 32; ++it) {
    int n = n0 + it*2 + rr;
    float v = emb[((size_t)b*N_ + n)*F_ + f];
    int hv = h[b*N_ + n];
    atomicAdd(&accl[hv*128 + f], v);
  }
  __syncthreads();
  for (int i = t; i < 4096; i += 256) pemb[(size_t)blockIdx.x*4096 + i] = accl[i];
}

// ---- K6: reduce partials (blocks 0..15: oadj; 16..79: out_emb -> d_out) ----
__global__ void k_reduce(const float* __restrict__ oadjp, const float* __restrict__ pemb,
                         float* __restrict__ oadj, float* __restrict__ out_emb) {
  int blk = blockIdx.x;
  if (blk < 16) {
    int i = blk*256 + threadIdx.x;      // [0,4096)
    int b = i >> 10, ii = i & 1023;
    float s = 0.f;
    const float* p = oadjp + (size_t)(b*256)*1024 + ii;
    for (int j = 0; j < 256; ++j) s += p[(size_t)j*1024];
    oadj[i] = s;
  } else {
    int i = (blk-16)*256 + threadIdx.x; // [0,16384)
    int b = i >> 12, ii = i & 4095;
    float s = 0.f;
    const float* p = pemb + (size_t)(b*64)*4096 + ii;
    for (int j = 0; j < 64; ++j) s += p[(size_t)j*4096];
    out_emb[i] = s;
  }
}

// ---- K7: finalize out_adj + scalars ----
__global__ void k_final(const float* __restrict__ numden_p, const float* __restrict__ oadj,
                        const float* __restrict__ ss, float* __restrict__ dout) {
  __shared__ float dsh[128];
  __shared__ float red[256];
  __shared__ float nd[8];
  int t = threadIdx.x;
  if (t < 8) {
    int b = t & 3;
    const float* p = numden_p + (t >> 2)*1024 + b*256;
    float s = 0.f;
    for (int j = 0; j < 256; ++j) s += p[j];
    nd[t] = s;
  }
  if (t >= 64 && t < 192) {
    int i = t - 64;
    int b = i >> 5, k = i & 31;
    float s = 0.f;
    for (int l = 0; l < 32; ++l) if (l != k) s += oadj[b*1024 + k*32 + l];
    dsh[i] = sqrtf(s) + EPS_;
  }
  __syncthreads();
  for (int i = t; i < 4096; i += 256) {
    int b = i >> 10, k = (i >> 5) & 31, l = i & 31;
    float v = (k == l) ? 0.f : oadj[i] / (dsh[b*32+k] * dsh[b*32+l]);
    dout[16384 + i] = v;
  }
  float a = 0.f;
  for (int i = t; i < 1024; i += 256) { float v = ss[i]; a += v*v; }
  red[t] = a; __syncthreads();
  for (int s2 = 128; s2; s2 >>= 1) { if (t < s2) red[t] += red[t+s2]; __syncthreads(); }
  float fro = sqrtf(red[0]);
  __syncthreads();
  float c = 0.f;
  float inv = 1.f / fro;
  float dk = (float)(1.0 / sqrt(32.0));
  for (int i = t; i < 1024; i += 256) {
    int k = i >> 5, l = i & 31;
    float v = ss[i]*inv - ((k == l) ? dk : 0.f);
    c += v*v;
  }
  red[t] = c; __syncthreads();
  for (int s2 = 128; s2; s2 >>= 1) { if (t < s2) red[t] += red[t+s2]; __syncthreads(); }
  if (t == 0) {
    dout[544769] = sqrtf(red[0]);
    float s = 0.f;
    for (int b = 0; b < 4; ++b) s += nd[b] / nd[4+b];
    dout[544768] = -s*0.25f;
  }
}

extern "C" void kernel_launch(void* const* d_in, const int* in_sizes, int n_in,
                              void* d_out, int out_size, void* d_ws, size_t ws_size,
                              hipStream_t stream) {
  const float* emb    = (const float*)d_in[0];
  const float* adj    = (const float*)d_in[1];
  const float* logits = (const float*)d_in[2];
  const float* gum    = (const float*)d_in[3];
  float* out = (float*)d_out;
  float* ws  = (float*)d_ws;

  float t1 = 0.99995f;
  float t2 = (float)(0.99995 * 0.99995);

  float* s_soft = ws + WS_SSOFT;
  float* sq     = ws + WS_SQ;
  float* ss     = ws + WS_SS;
  bf16x8* wfs   = (bf16x8*)(ws + WS_WFS);
  bf16x8* wfh   = (bf16x8*)(ws + WS_WFH);
  float* oadjp  = ws + WS_OADJP;
  float* ndp    = ws + WS_NUMDEN;
  float* pemb   = ws + WS_PEMB;
  float* oadj   = ws + WS_OADJ;
  int* hbuf     = (int*)(ws + WS_H);

  (void)hipMemsetAsync(ss, 0, 1024 * sizeof(float), stream);

  k_pre   <<<64, 256, 0, stream>>>(logits, gum, s_soft, sq, ss, out + 20480, hbuf, wfs, wfh, t1, t2);
  k_gemm  <<<1024, 256, 0, stream>>>(adj, wfs, wfh, s_soft, sq, hbuf, ndp, oadjp);
  k_outemb<<<256, 256, 0, stream>>>(emb, hbuf, pemb);
  k_reduce<<<80, 256, 0, stream>>>(oadjp, pemb, oadj, out);
  k_final <<<1, 256, 0, stream>>>(ndp, oadj, ss, out);
}

// Round 3
// 416.780 us; speedup vs baseline: 1.0562x; 1.0195x over previous
//
#include <hip/hip_runtime.h>
#include <hip/hip_bf16.h>
#include <math.h>

#define B_ 4
#define N_ 4096
#define F_ 128
#define K_ 32
#define EPS_ 1e-8f

typedef __attribute__((ext_vector_type(8))) __bf16 bf16x8;
typedef __attribute__((ext_vector_type(4))) float f32x4;

// ws float-index layout
#define WS_SSOFT   0          // 131072
#define WS_SQ      131072     // 4096
#define WS_SSP     135168     // 64 blocks * 1024 = 65536 (ss partials, no memset needed)
#define WS_WFS     200704     // [N/32][2][64] bf16x8 = 256KB = 65536 float-equiv
#define WS_WFH     266240     // [B][N/32][2][64] bf16x8 = 1MB = 262144 float-equiv
#define WS_OADJP   528384     // 1024 gemm blocks * 1024 = 1048576
#define WS_NUMDEN  1576960    // 2048
#define WS_PEMB    1579008    // 256 blocks * 4096 = 1048576
#define WS_H       2627584    // B*N ints

// ---- K_pre: fused s_soft softmax + ss partials + gumbel hard-sample + W-fragment build.
__global__ void k_pre(const float* __restrict__ logits, const float* __restrict__ gum,
                      float* __restrict__ s_soft, float* __restrict__ sq,
                      float* __restrict__ ssp, float* __restrict__ s_sample,
                      int* __restrict__ h, bf16x8* __restrict__ wfs,
                      bf16x8* __restrict__ wfh, float t1, float t2) {
  __shared__ float sl[64][33];
  __shared__ int hl[4][64];
  int t = threadIdx.x;
  int r = blockIdx.x;
  int n0 = r * 64;

  // phase 1: soft softmax (64 rows, t<64)
  if (t < 64) {
    int n = n0 + t;
    float z[32];
    float mx = -1e30f;
    for (int k = 0; k < 32; ++k) { z[k] = logits[n*32+k] / t2; mx = fmaxf(mx, z[k]); }
    float s = 0.f;
    for (int k = 0; k < 32; ++k) { z[k] = expf(z[k]-mx); s += z[k]; }
    float sqa = 0.f;
    for (int k = 0; k < 32; ++k) {
      float v = z[k] / s;
      s_soft[n*32+k] = v;
      sl[t][k] = v;
      sqa += v*v;
    }
    sq[n] = sqa;
  }

  // phase 2: gumbel hard sample, thread t -> (b = t>>6, row n0 + (t&63))
  {
    int b = t >> 6, nn = t & 63;
    int n = n0 + nn;
    size_t i = (size_t)b * N_ + n;
    float z[32];
    float mx = -1e30f;
    for (int k = 0; k < 32; ++k) { z[k] = logits[n*32+k]/t1 + gum[i*32+k]; mx = fmaxf(mx, z[k]); }
    float s = 0.f;
    for (int k = 0; k < 32; ++k) { z[k] = expf(z[k]-mx); s += z[k]; }
    int am = 0; float best = -1.f;
    for (int k = 0; k < 32; ++k) { z[k] = z[k]/s; if (z[k] > best) { best = z[k]; am = k; } }
    for (int k = 0; k < 32; ++k) {
      float yh = (k==am) ? 1.f : 0.f;
      s_sample[i*32+k] = (yh - z[k]) + z[k] + EPS_;
    }
    h[i] = am;
    hl[b][nn] = am;
  }
  __syncthreads();

  // phase 3: ss[K,K] partial for this block (no atomics; reduced in k_post)
  for (int pp = 0; pp < 4; ++pp) {
    int p = pp*256 + t;
    int k = p >> 5, l = p & 31;
    float a = 0.f;
    for (int rr = 0; rr < 64; ++rr) a += sl[rr][k]*sl[rr][l];
    ssp[(size_t)r*1024 + p] = a;
  }

  // phase 4: wfs fragments (batch-independent s_soft columns 0..31)
  {
    int lane = t & 63;
    int c = (t >> 6) & 1;
    int tts = t >> 7;               // 0..1
    int col = c*16 + (lane & 15);
    int lrow = tts*32 + (lane >> 4)*8;
    bf16x8 v;
    #pragma unroll
    for (int j = 0; j < 8; ++j) v[j] = (__bf16)sl[lrow+j][col];
    wfs[((size_t)(2*r + tts)*2 + c)*64 + lane] = v;
  }

  // phase 5: wfh fragments (one-hot columns 32..63), 4 batches
  for (int it = 0; it < 4; ++it) {
    int p = it*256 + t;
    int lane = p & 63;
    int c = (p >> 6) & 1;
    int tts = (p >> 7) & 1;
    int b = p >> 8;
    int cc = c*16 + (lane & 15);
    int lrow = tts*32 + (lane >> 4)*8;
    bf16x8 v;
    #pragma unroll
    for (int j = 0; j < 8; ++j) v[j] = (__bf16)((hl[b][lrow+j] == cc) ? 1.f : 0.f);
    wfh[(((size_t)b*(N_/32) + 2*r + tts)*2 + c)*64 + lane] = v;
  }
}

#define NT(p) __builtin_nontemporal_load((const f32x4*)(p))

// ---- K_gemm: blocks 0..255 = out_emb pooling (runs concurrent with the GEMM,
// hiding under its BW stream); blocks 256..1279 = Y = adj @ [s_soft | H] GEMM.
// GEMM: grid B * 32 rowblocks * 8 splitm; block = 128 rows x 64 cols, m-chunk 512.
__launch_bounds__(256, 4)
__global__ void k_gemm(const float* __restrict__ adj, const float* __restrict__ emb,
                       const bf16x8* __restrict__ wfs, const bf16x8* __restrict__ wfh,
                       const float* __restrict__ s_soft, const float* __restrict__ sq,
                       const int* __restrict__ h, float* __restrict__ numden_p,
                       float* __restrict__ oadjp, float* __restrict__ pemb) {
  __shared__ float sh[4096];
  __shared__ float rn[4], rd[4];
  int t = threadIdx.x;
  int bid = blockIdx.x;

  if (bid < 256) {
    // ---- out_emb partial pooling (64 rows per block) ----
    for (int i = t; i < 4096; i += 256) sh[i] = 0.f;
    __syncthreads();
    int b = bid >> 6;
    int n0 = (bid & 63) * 64;
    int f = t & 127, rr = t >> 7;
    for (int it = 0; it < 32; ++it) {
      int n = n0 + it*2 + rr;
      float v = emb[((size_t)b*N_ + n)*F_ + f];
      int hv = h[b*N_ + n];
      atomicAdd(&sh[hv*128 + f], v);
    }
    __syncthreads();
    for (int i = t; i < 4096; i += 256) pemb[(size_t)bid*4096 + i] = sh[i];
    return;
  }

  int gid = bid - 256;
  int w = t >> 6, l = t & 63;
  int lr = l & 15, lhi = l >> 4;
  int sp = gid & 7, r = (gid >> 3) & 31, b = gid >> 8;
  float* oal = sh;   // first 1024 floats

  for (int i = t; i < 1024; i += 256) oal[i] = 0.f;
  __syncthreads();

  int row0 = r*128;
  int m0 = sp*512;
  int rowA = row0 + w*32 + lr;          // rt=0 row for this lane

  const float* pA0 = adj + (size_t)b*N_*N_ + (size_t)rowA*N_ + m0 + lhi*8;
  const float* pA1 = pA0 + (size_t)16*N_;
  const bf16x8* pws = wfs + (size_t)(m0 >> 5)*128 + l;
  const bf16x8* pwh = wfh + ((size_t)b*(N_/32) + (m0 >> 5))*128 + l;

  f32x4 acc00 = {0,0,0,0}, acc01 = {0,0,0,0}, acc02 = {0,0,0,0}, acc03 = {0,0,0,0};
  f32x4 acc10 = {0,0,0,0}, acc11 = {0,0,0,0}, acc12 = {0,0,0,0}, acc13 = {0,0,0,0};

  // prime chunk 0
  f32x4 a0lo = NT(pA0), a0hi = NT(pA0 + 4);
  f32x4 a1lo = NT(pA1), a1hi = NT(pA1 + 4);
  bf16x8 wc0 = pws[0], wc1 = pws[64], wc2 = pwh[0], wc3 = pwh[64];

  #pragma unroll 1
  for (int c = 0; c < 16; ++c) {
    f32x4 n0lo, n0hi, n1lo, n1hi;
    bf16x8 wn0, wn1, wn2, wn3;
    if (c < 15) {
      pA0 += 32; pA1 += 32; pws += 128; pwh += 128;
      n0lo = NT(pA0); n0hi = NT(pA0 + 4);
      n1lo = NT(pA1); n1hi = NT(pA1 + 4);
      wn0 = pws[0]; wn1 = pws[64]; wn2 = pwh[0]; wn3 = pwh[64];
    }
    bf16x8 fa0, fa1;
    #pragma unroll
    for (int j = 0; j < 4; ++j) {
      fa0[j]   = (__bf16)a0lo[j];
      fa0[j+4] = (__bf16)a0hi[j];
      fa1[j]   = (__bf16)a1lo[j];
      fa1[j+4] = (__bf16)a1hi[j];
    }
    acc00 = __builtin_amdgcn_mfma_f32_16x16x32_bf16(fa0, wc0, acc00, 0, 0, 0);
    acc01 = __builtin_amdgcn_mfma_f32_16x16x32_bf16(fa0, wc1, acc01, 0, 0, 0);
    acc02 = __builtin_amdgcn_mfma_f32_16x16x32_bf16(fa0, wc2, acc02, 0, 0, 0);
    acc03 = __builtin_amdgcn_mfma_f32_16x16x32_bf16(fa0, wc3, acc03, 0, 0, 0);
    acc10 = __builtin_amdgcn_mfma_f32_16x16x32_bf16(fa1, wc0, acc10, 0, 0, 0);
    acc11 = __builtin_amdgcn_mfma_f32_16x16x32_bf16(fa1, wc1, acc11, 0, 0, 0);
    acc12 = __builtin_amdgcn_mfma_f32_16x16x32_bf16(fa1, wc2, acc12, 0, 0, 0);
    acc13 = __builtin_amdgcn_mfma_f32_16x16x32_bf16(fa1, wc3, acc13, 0, 0, 0);
    if (c < 15) {
      a0lo = n0lo; a0hi = n0hi; a1lo = n1lo; a1hi = n1hi;
      wc0 = wn0; wc1 = wn1; wc2 = wn2; wc3 = wn3;
    }
  }

  // epilogue: C-frag lane l holds col = c*16 + (l&15), rows row0 + w*32 + rt*16 + (l>>4)*4 + i
  float numacc = 0.f, denacc = 0.f;
  {
    f32x4 a0s[2] = {acc00, acc10}, a1s[2] = {acc01, acc11};
    f32x4 a2s[2] = {acc02, acc12}, a3s[2] = {acc03, acc13};
    int wrow0 = row0 + w*32;
    #pragma unroll
    for (int rt = 0; rt < 2; ++rt) {
      int rbase = wrow0 + rt*16 + lhi*4;
      #pragma unroll
      for (int i = 0; i < 4; ++i) {
        int row = rbase + i;
        float sqv = sq[row];
        int hv = h[b*N_ + row];
        numacc += a0s[rt][i] * s_soft[row*32 + lr];
        numacc += a1s[rt][i] * s_soft[row*32 + 16 + lr];
        float v2 = a2s[rt][i], v3 = a3s[rt][i];
        denacc += (v2 + v3) * sqv;
        atomicAdd(&oal[hv*32 + lr], v2);
        atomicAdd(&oal[hv*32 + 16 + lr], v3);
      }
    }
  }
  for (int off = 32; off; off >>= 1) {
    numacc += __shfl_down(numacc, off);
    denacc += __shfl_down(denacc, off);
  }
  if (l == 0) { rn[w] = numacc; rd[w] = denacc; }
  __syncthreads();
  if (t == 0) {
    numden_p[gid] = rn[0]+rn[1]+rn[2]+rn[3];
    numden_p[1024 + gid] = rd[0]+rd[1]+rd[2]+rd[3];
  }
  for (int i = t; i < 1024; i += 256) oadjp[(size_t)gid*1024 + i] = oal[i];
}

// ---- K_post: blocks 0..63 reduce out_emb; 64..67 finalize out_adj per batch;
// block 68 computes mincut + ortho scalars. ----
__global__ void k_post(const float* __restrict__ oadjp, const float* __restrict__ pemb,
                       const float* __restrict__ ndp, const float* __restrict__ ssp,
                       float* __restrict__ dout) {
  int blk = blockIdx.x;
  int t = threadIdx.x;
  if (blk < 64) {
    int i = blk*256 + t;                // [0,16384)
    int b = i >> 12, ii = i & 4095;
    float s = 0.f;
    const float* p = pemb + (size_t)(b*64)*4096 + ii;
    for (int j = 0; j < 64; ++j) s += p[(size_t)j*4096];
    dout[i] = s;
  } else if (blk < 68) {
    __shared__ float oal[1024];
    __shared__ float dsh[32];
    int b = blk - 64;
    float a0 = 0.f, a1 = 0.f, a2 = 0.f, a3 = 0.f;
    const float* p = oadjp + (size_t)b*256*1024 + t;
    for (int j = 0; j < 256; ++j) {
      a0 += p[0]; a1 += p[256]; a2 += p[512]; a3 += p[768];
      p += 1024;
    }
    oal[t] = a0; oal[t+256] = a1; oal[t+512] = a2; oal[t+768] = a3;
    __syncthreads();
    if (t < 32) {
      float s = 0.f;
      for (int l = 0; l < 32; ++l) if (l != t) s += oal[t*32+l];
      dsh[t] = sqrtf(s) + EPS_;
    }
    __syncthreads();
    for (int i = t; i < 1024; i += 256) {
      int k = i >> 5, l = i & 31;
      float v = (k == l) ? 0.f : oal[i] / (dsh[k] * dsh[l]);
      dout[16384 + b*1024 + i] = v;
    }
  } else {
    __shared__ float red[256];
    __shared__ float nd[8];
    if (t < 8) {
      int b = t & 3;
      const float* p = ndp + (t >> 2)*1024 + b*256;
      float s = 0.f;
      for (int j = 0; j < 256; ++j) s += p[j];
      nd[t] = s;
    }
    // reduce ss partials: each thread owns entries t, t+256, t+512, t+768
    float v0 = 0.f, v1 = 0.f, v2 = 0.f, v3 = 0.f;
    for (int r = 0; r < 64; ++r) {
      const float* p = ssp + (size_t)r*1024 + t;
      v0 += p[0]; v1 += p[256]; v2 += p[512]; v3 += p[768];
    }
    float a = v0*v0 + v1*v1 + v2*v2 + v3*v3;
    red[t] = a; __syncthreads();
    for (int s2 = 128; s2; s2 >>= 1) { if (t < s2) red[t] += red[t+s2]; __syncthreads(); }
    float fro = sqrtf(red[0]);
    __syncthreads();
    float inv = 1.f / fro;
    float dk = (float)(1.0 / sqrt(32.0));
    float c = 0.f;
    {
      float w;
      int p0 = t, p1 = t+256, p2 = t+512, p3 = t+768;
      w = v0*inv - (((p0>>5)==(p0&31)) ? dk : 0.f); c += w*w;
      w = v1*inv - (((p1>>5)==(p1&31)) ? dk : 0.f); c += w*w;
      w = v2*inv - (((p2>>5)==(p2&31)) ? dk : 0.f); c += w*w;
      w = v3*inv - (((p3>>5)==(p3&31)) ? dk : 0.f); c += w*w;
    }
    red[t] = c; __syncthreads();
    for (int s2 = 128; s2; s2 >>= 1) { if (t < s2) red[t] += red[t+s2]; __syncthreads(); }
    if (t == 0) {
      dout[544769] = sqrtf(red[0]);
      float s = 0.f;
      for (int b = 0; b < 4; ++b) s += nd[b] / nd[4+b];
      dout[544768] = -s*0.25f;
    }
  }
}

extern "C" void kernel_launch(void* const* d_in, const int* in_sizes, int n_in,
                              void* d_out, int out_size, void* d_ws, size_t ws_size,
                              hipStream_t stream) {
  const float* emb    = (const float*)d_in[0];
  const float* adj    = (const float*)d_in[1];
  const float* logits = (const float*)d_in[2];
  const float* gum    = (const float*)d_in[3];
  float* out = (float*)d_out;
  float* ws  = (float*)d_ws;

  float t1 = 0.99995f;
  float t2 = (float)(0.99995 * 0.99995);

  float* s_soft = ws + WS_SSOFT;
  float* sq     = ws + WS_SQ;
  float* ssp    = ws + WS_SSP;
  bf16x8* wfs   = (bf16x8*)(ws + WS_WFS);
  bf16x8* wfh   = (bf16x8*)(ws + WS_WFH);
  float* oadjp  = ws + WS_OADJP;
  float* ndp    = ws + WS_NUMDEN;
  float* pemb   = ws + WS_PEMB;
  int* hbuf     = (int*)(ws + WS_H);

  k_pre  <<<64, 256, 0, stream>>>(logits, gum, s_soft, sq, ssp, out + 20480, hbuf, wfs, wfh, t1, t2);
  k_gemm <<<1280, 256, 0, stream>>>(adj, emb, wfs, wfh, s_soft, sq, hbuf, ndp, oadjp, pemb);
  k_post <<<69, 256, 0, stream>>>(oadjp, pemb, ndp, ssp, out);
}